// Round 14
// baseline (388.480 us; speedup 1.0000x reference)
//
#include <hip/hip_runtime.h>
#include <hip/hip_bf16.h>

// Problem dims
#define B_    4
#define T_    2048
#define D_    1024
#define DH_   1024
#define DFF_  4096
#define MTOT  (B_ * T_)   // 8192 rows

using f32x4  = __attribute__((ext_vector_type(4))) float;
using bf16x8 = __attribute__((ext_vector_type(8))) short;

__device__ __forceinline__ unsigned short f2bf(float f) {
    unsigned u = __builtin_bit_cast(unsigned, f);
    u += 0x7fffu + ((u >> 16) & 1u);     // round-to-nearest-even
    return (unsigned short)(u >> 16);
}
__device__ __forceinline__ float bf2f(unsigned short h) {
    unsigned u = ((unsigned)h) << 16;
    return __builtin_bit_cast(float, u);
}

// async global->LDS, 16B per lane; LDS dest is wave-uniform base + lane*16
__device__ __forceinline__ void gload16(const short* g, short* l) {
    __builtin_amdgcn_global_load_lds(
        (const __attribute__((address_space(1))) unsigned int*)g,
        (__attribute__((address_space(3))) unsigned int*)l, 16, 0, 0);
}

// ---------------- weight transpose + fp32->bf16 convert ----------------
__global__ __launch_bounds__(256) void transp_f32_bf16(
    const float* __restrict__ src, short* __restrict__ dst, int K, int N) {
    __shared__ float tile[32][33];
    int tk = blockIdx.y * 32, tn = blockIdx.x * 32;
    int tx = threadIdx.x & 31, ty = threadIdx.x >> 5;   // 32 x 8
#pragma unroll
    for (int i = 0; i < 4; i++) {
        int r = ty + i * 8;
        tile[r][tx] = src[(size_t)(tk + r) * N + tn + tx];
    }
    __syncthreads();
#pragma unroll
    for (int i = 0; i < 4; i++) {
        int r = ty + i * 8;   // n offset
        dst[(size_t)(tn + r) * K + tk + tx] = f2bf(tile[tx][r]);
    }
}

__global__ void copyv(const float* __restrict__ s, float* __restrict__ d, int n) {
    int i = blockIdx.x * blockDim.x + threadIdx.x;
    if (i < n) d[i] = s[i];
}

// ---------------- LayerNorm (fp32 in, bf16 out), one block per row ----------------
__global__ __launch_bounds__(256) void ln_rows(
    const float* __restrict__ x, const float* __restrict__ g,
    const float* __restrict__ bta, short* __restrict__ out) {
    int row = blockIdx.x;
    const float* xr = x + (size_t)row * D_;
    int t = threadIdx.x;
    float4 v = *(const float4*)(xr + t * 4);
    float s  = v.x + v.y + v.z + v.w;
    float s2 = v.x * v.x + v.y * v.y + v.z * v.z + v.w * v.w;
#pragma unroll
    for (int off = 1; off < 64; off <<= 1) {
        s  += __shfl_xor(s, off);
        s2 += __shfl_xor(s2, off);
    }
    __shared__ float as_[4], as2_[4];
    int wave = t >> 6, lane = t & 63;
    if (lane == 0) { as_[wave] = s; as2_[wave] = s2; }
    __syncthreads();
    s  = as_[0] + as_[1] + as_[2] + as_[3];
    s2 = as2_[0] + as2_[1] + as2_[2] + as2_[3];
    float mean = s * (1.0f / D_);
    float var  = s2 * (1.0f / D_) - mean * mean;
    float rstd = rsqrtf(var + 1e-5f);
    float4 gv = *(const float4*)(g + t * 4);
    float4 bv = *(const float4*)(bta + t * 4);
    short4 o;
    o.x = f2bf((v.x - mean) * rstd * gv.x + bv.x);
    o.y = f2bf((v.y - mean) * rstd * gv.y + bv.y);
    o.z = f2bf((v.z - mean) * rstd * gv.z + bv.z);
    o.w = f2bf((v.w - mean) * rstd * gv.w + bv.w);
    *(short4*)(out + (size_t)row * D_ + t * 4) = o;
}

// ---------------- tiled GEMM: C[m][n] = sum_k A[m][k]*Bt[n][k] ----------------
// BM=256, BN=64*NB, BK=32, 8 waves (2M x 4N), per-wave 128 x 16*NB (acc[8][NB]).
// SINGLE-BARRIER K-tile, structurally-overlapped: 4-slot A + 4-slot B LDS;
// DMA issues tile t+3 (slot (t+3)&3 == (t-1)&3, last read 2 barriers ago);
// tile t: { rd frags(t+1) [slot landed, drained end of t-1]  ||  MFMA(t)
// [regs preloaded in t-1 -> NO in-tile dependence, compiler interleaves];
// issue DMA(t+3); vmcnt(calls/tile); s_barrier }.  lgkm slack = 1 tile;
// vmcnt slack = 1 tile (> HBM latency). De-pinned (no manual lgkm/sched walls).
// Swizzle (64B rows): byte ^= ((row&6)<<3) -> 2-way banks (free); inverse on
// global DMA source, linear LDS dest. XCD-chunked + 4-wide supertile order.
// ACT: 0 none, 1 exact GELU, 2 attn-exp (unnormalized P + row-sum partials).
// RES: 0 none, 1 +res, 2 normalize by 8-way row-sum partials then +res.
template<int NB, int BIAS_MODE, int ACT, int RES, int OUT_BF16>
__global__ __launch_bounds__(512, 2) void gemmT(
    const short* __restrict__ A, int lda, long long sA,
    const short* __restrict__ Bt, int ldb, long long sB,
    void* __restrict__ C, int ldc, long long sC,
    const float* __restrict__ bias,
    const float* __restrict__ res, int ldr, long long sR,
    int K) {
    constexpr int BSLOT = (NB == 4 ? 8192 : 4096);   // B slot shorts
    extern __shared__ short smem_[];
    short* shA = smem_;                 // 4 slots x 8192 shorts (16KB)
    short* shB = smem_ + 32768;         // 4 slots x BSLOT

    // ---- XCD-chunked bijective swizzle + 4-wide bn supertile strips ----
    int gx = gridDim.x, gy = gridDim.y;
    int n2d = gx * gy;
    int nwg = n2d * gridDim.z;
    int lid = blockIdx.x + gx * (blockIdx.y + gy * blockIdx.z);
    int q = nwg >> 3, rq = nwg & 7, xcd = lid & 7, i_ = lid >> 3;
    int nid = (xcd < rq ? xcd * (q + 1) : rq * (q + 1) + (xcd - rq) * q) + i_;
    int z = nid / n2d, r2d = nid % n2d;
    int sw = gy << 2;                          // requires gx % 4 == 0
    int strip = r2d / sw, rr = r2d % sw;
    int by = rr >> 2, bx = (strip << 2) + (rr & 3);

    int bm = by * 256, bn = bx * (64 * NB);
    const short* gA = A  + (size_t)z * sA + (size_t)bm * lda;
    const short* gB = Bt + (size_t)z * sB + (size_t)bn * ldb;
    int tid = threadIdx.x, lane = tid & 63, w = tid >> 6;
    int wr = w >> 2, wc = w & 3;

    // staging: one gload16 set covers 128 rows x 64B (8KB). A: 2 sets (256 rows);
    // B: NB==4 ? 2 sets : 1 set. Global col carries the inverse swizzle.
    int rbase = tid >> 2;                                    // 0..127
    int gcol  = ((((tid & 3) << 4) ^ ((rbase & 6) << 3)) >> 1);
    const short* pA[2]; const short* pB[2];
#pragma unroll
    for (int c = 0; c < 2; c++)
        pA[c] = gA + (size_t)(c * 128 + rbase) * lda + gcol;
    pB[0] = gB + (size_t)rbase * ldb + gcol;
    if constexpr (NB == 4) pB[1] = gB + (size_t)(128 + rbase) * ldb + gcol;

    // fragment ds_read byte offsets: row*64 + ((lane>>4)*16 ^ ((row&6)<<3))
    int aoff[8], boff[4];
#pragma unroll
    for (int f = 0; f < 8; f++) {
        int row = wr * 128 + f * 16 + (lane & 15);
        aoff[f] = row * 64 + (((lane >> 4) * 16) ^ ((row & 6) << 3));
    }
#pragma unroll
    for (int f = 0; f < NB; f++) {
        int row = wc * (16 * NB) + f * 16 + (lane & 15);
        boff[f] = row * 64 + (((lane >> 4) * 16) ^ ((row & 6) << 3));
    }

    int nk = K >> 5;                    // K/32; 32/64/128 here (even)
    f32x4 acc[8][NB] = {};

    // prologue: issue tiles 0,1,2; drain tiles 0,1 (leave tile2's calls)
#pragma unroll
    for (int s = 0; s < 3; s++) {
        short* dA = shA + s * 8192;
        short* dB = shB + s * BSLOT;
        gload16(pA[0] + s * 32, dA + tid * 8);
        gload16(pA[1] + s * 32, dA + 4096 + tid * 8);
        gload16(pB[0] + s * 32, dB + tid * 8);
        if constexpr (NB == 4) gload16(pB[1] + s * 32, dB + 4096 + tid * 8);
    }
    if constexpr (NB == 4) asm volatile("s_waitcnt vmcnt(4)" ::: "memory");
    else                   asm volatile("s_waitcnt vmcnt(3)" ::: "memory");
    __builtin_amdgcn_s_barrier();

    // preload tile-0 frags
    bf16x8 cA[8], cB[4], nA[8], nB[4];
#pragma unroll
    for (int f = 0; f < 8; f++) cA[f] = *(const bf16x8*)((const char*)shA + aoff[f]);
#pragma unroll
    for (int f = 0; f < NB; f++) cB[f] = *(const bf16x8*)((const char*)shB + boff[f]);

#define MFROW(r_, av, bv) \
    _Pragma("unroll") \
    for (int n_ = 0; n_ < NB; n_++) \
        acc[r_][n_] = __builtin_amdgcn_mfma_f32_16x16x32_bf16(av, bv[n_], acc[r_][n_], 0, 0, 0);

    // tile body: rd frags(t+1) || MFMA(t); DMA(t+3); vmcnt; barrier
#define TILE(T, uA, uB, vA, vB) { \
    int t = (T); \
    const char* sA1 = (const char*)(shA + ((t + 1) & 3) * 8192); \
    const char* sB1 = (const char*)(shB + ((t + 1) & 3) * BSLOT); \
    short* wA = shA + ((t + 3) & 3) * 8192; \
    short* wB = shB + ((t + 3) & 3) * BSLOT; \
    int kk = (t + 3 < nk ? t + 3 : nk - 1) << 5; \
    _Pragma("unroll") \
    for (int f = 0; f < 8; f++) vA[f] = *(const bf16x8*)(sA1 + aoff[f]); \
    _Pragma("unroll") \
    for (int f = 0; f < NB; f++) vB[f] = *(const bf16x8*)(sB1 + boff[f]); \
    gload16(pA[0] + kk, wA + tid * 8); \
    gload16(pA[1] + kk, wA + 4096 + tid * 8); \
    gload16(pB[0] + kk, wB + tid * 8); \
    if constexpr (NB == 4) gload16(pB[1] + kk, wB + 4096 + tid * 8); \
    MFROW(0, uA[0], uB) MFROW(1, uA[1], uB) MFROW(2, uA[2], uB) MFROW(3, uA[3], uB) \
    MFROW(4, uA[4], uB) MFROW(5, uA[5], uB) MFROW(6, uA[6], uB) MFROW(7, uA[7], uB) \
    if constexpr (NB == 4) asm volatile("s_waitcnt vmcnt(4)" ::: "memory"); \
    else                   asm volatile("s_waitcnt vmcnt(3)" ::: "memory"); \
    __builtin_amdgcn_s_barrier(); }

    for (int tp = 0; tp < nk; tp += 2) {
        TILE(tp,     cA, cB, nA, nB)
        TILE(tp + 1, nA, nB, cA, cB)
    }
#undef TILE
#undef MFROW
    asm volatile("s_waitcnt vmcnt(0)" ::: "memory");   // drain tail DMA
    __syncthreads();   // all waves' DMAs landed before lpart reuse

    // epilogue: C/D layout col = lane&15, row = (lane>>4)*4 + r  [m89/m91 verified]
    size_t zc = (size_t)z * (size_t)sC;
    float* lpart = (float*)smem_;   // [4 wc][256 rows] reuse (ACT==2)
#pragma unroll
    for (int fr = 0; fr < 8; fr++) {
        float pr[4] = {0.f, 0.f, 0.f, 0.f};
        float s8[4];
        if (RES == 2) {
#pragma unroll
            for (int r_ = 0; r_ < 4; r_++) {
                int row = bm + wr * 128 + fr * 16 + (lane >> 4) * 4 + r_;
                float s = 0.f;
#pragma unroll
                for (int i = 0; i < 8; i++) s += bias[((size_t)z * 8 + i) * 2048 + row];
                s8[r_] = 1.0f / s;
            }
        }
#pragma unroll
        for (int fn = 0; fn < NB; fn++) {
            int colc = bn + wc * (16 * NB) + fn * 16 + (lane & 15);
#pragma unroll
            for (int r_ = 0; r_ < 4; r_++) {
                int row = bm + wr * 128 + fr * 16 + (lane >> 4) * 4 + r_;
                float v = acc[fr][fn][r_];
                if (BIAS_MODE == 1) v += bias[colc];
                else if (BIAS_MODE == 2) v += bias[row];
                if (ACT == 1) v = 0.5f * v * (1.0f + erff(v * 0.70710678118654752f));
                if (ACT == 2) {
                    // unnormalized attention prob: no max-subtraction needed
                    v = expf(v * 0.03125f);
                    unsigned short us = f2bf(v);
                    ((short*)C)[zc + (size_t)row * ldc + colc] = (short)us;
                    pr[r_] += bf2f(us);   // sum ROUNDED values -> exact normalization
                    continue;
                }
                if (RES == 1) v += res[(size_t)z * sR + (size_t)row * ldr + colc];
                if (RES == 2) v = v * s8[r_] + res[(size_t)z * sR + (size_t)row * ldr + colc];
                if (OUT_BF16) ((short*)C)[zc + (size_t)row * ldc + colc] = f2bf(v);
                else          ((float*)C)[zc + (size_t)row * ldc + colc] = v;
            }
        }
        if (ACT == 2) {
            // reduce across the 16 lanes sharing each row (cols), deterministic
#pragma unroll
            for (int m_ = 1; m_ < 16; m_ <<= 1) {
#pragma unroll
                for (int r_ = 0; r_ < 4; r_++) pr[r_] += __shfl_xor(pr[r_], m_);
            }
            if ((lane & 15) == 0) {
#pragma unroll
                for (int r_ = 0; r_ < 4; r_++)
                    lpart[wc * 256 + wr * 128 + fr * 16 + (lane >> 4) * 4 + r_] = pr[r_];
            }
        }
    }
    if (ACT == 2) {
        __syncthreads();
        if (tid < 256) {
            float s = lpart[tid] + lpart[256 + tid] + lpart[512 + tid] + lpart[768 + tid];
            ((float*)res)[((size_t)z * 8 + bx) * 2048 + bm + tid] = s;
        }
    }
}

#define SHB4 131072   // NB=4: 4x16KB A + 4x16KB B
#define SHB2 98304    // NB=2: 4x16KB A + 4x8KB B

extern "C" void kernel_launch(void* const* d_in, const int* in_sizes, int n_in,
                              void* d_out, int out_size, void* d_ws, size_t ws_size,
                              hipStream_t stream) {
    const float* x    = (const float*)d_in[0];
    const float* ln1g = (const float*)d_in[1];
    const float* ln1b = (const float*)d_in[2];
    const float* Wq   = (const float*)d_in[3];
    const float* bq   = (const float*)d_in[4];
    const float* Wk   = (const float*)d_in[5];
    const float* bk   = (const float*)d_in[6];
    const float* Wv   = (const float*)d_in[7];
    const float* bv   = (const float*)d_in[8];
    const float* ln2g = (const float*)d_in[9];
    const float* ln2b = (const float*)d_in[10];
    const float* Win  = (const float*)d_in[11];
    const float* bin  = (const float*)d_in[12];
    const float* Wout = (const float*)d_in[13];
    const float* bout = (const float*)d_in[14];

    char* ws = (char*)d_ws;
    size_t off = 0;
    auto alloc = [&](size_t bytes) {
        void* p = ws + off;
        off += (bytes + 255) & ~(size_t)255;
        return p;
    };
    short* WqkT  = (short*)alloc((size_t)2048 * 1024 * 2);  // [2048][1024] = [Wq^T ; Wk^T]
    short* WvT   = (short*)alloc((size_t)1024 * 1024 * 2);  // [1024][1024]
    short* WinT  = (short*)alloc((size_t)4096 * 1024 * 2);  // [4096][1024]
    short* WoutT = (short*)alloc((size_t)1024 * 4096 * 2);  // [1024][4096]
    float* bqk   = (float*)alloc((size_t)2048 * 4);
    short* h     = (short*)alloc((size_t)MTOT * 1024 * 2);  // LN output (reused for LN2)
    short* QK    = (short*)alloc((size_t)MTOT * 2048 * 2);  // [8192][2048] = [Q | K]
    short* VT    = (short*)alloc((size_t)1024 * 8192 * 2);  // V^T [1024][8192]
    float* S     = (float*)alloc((size_t)4 * 2048 * 2048 * 4); // P bf16 (ld 4096 sh) + ff alias
    float* x1    = (float*)alloc((size_t)MTOT * 1024 * 4);  // x + attn_out (fp32)
    float* rowsums = (float*)alloc((size_t)4 * 8 * 2048 * 4); // per-bn-block partial row sums
    (void)ws_size; (void)in_sizes; (void)n_in; (void)out_size;

    hipFuncSetAttribute((const void*)gemmT<4,1,0,0,1>, hipFuncAttributeMaxDynamicSharedMemorySize, SHB4);
    hipFuncSetAttribute((const void*)gemmT<4,0,2,0,1>, hipFuncAttributeMaxDynamicSharedMemorySize, SHB4);
    hipFuncSetAttribute((const void*)gemmT<4,1,1,0,1>, hipFuncAttributeMaxDynamicSharedMemorySize, SHB4);
    hipFuncSetAttribute((const void*)gemmT<2,2,0,0,1>, hipFuncAttributeMaxDynamicSharedMemorySize, SHB2);
    hipFuncSetAttribute((const void*)gemmT<2,0,0,2,0>, hipFuncAttributeMaxDynamicSharedMemorySize, SHB2);
    hipFuncSetAttribute((const void*)gemmT<2,1,0,1,0>, hipFuncAttributeMaxDynamicSharedMemorySize, SHB2);

    // --- weights -> bf16 [N][K] ---
    transp_f32_bf16<<<dim3(32, 32), 256, 0, stream>>>(Wq, WqkT, 1024, 1024);
    transp_f32_bf16<<<dim3(32, 32), 256, 0, stream>>>(Wk, WqkT + (size_t)1024 * 1024, 1024, 1024);
    transp_f32_bf16<<<dim3(32, 32), 256, 0, stream>>>(Wv, WvT, 1024, 1024);
    transp_f32_bf16<<<dim3(128, 32), 256, 0, stream>>>(Win, WinT, 1024, 4096);
    transp_f32_bf16<<<dim3(32, 128), 256, 0, stream>>>(Wout, WoutT, 4096, 1024);
    copyv<<<4, 256, 0, stream>>>(bq, bqk, 1024);
    copyv<<<4, 256, 0, stream>>>(bk, bqk + 1024, 1024);

    // --- LN1: x -> h (bf16) ---
    ln_rows<<<MTOT, 256, 0, stream>>>(x, ln1g, ln1b, h);

    // --- [Q|K] = h @ [Wq|Wk] + bias : M=8192 N=2048 K=1024, bf16 ---
    gemmT<4, 1, 0, 0, 1><<<dim3(8, 32, 1), 512, SHB4, stream>>>(
        h, 1024, 0, WqkT, 1024, 0, QK, 2048, 0, bqk, nullptr, 0, 0, 1024);

    // --- V^T = Wv^T @ h^T + bv(row): M=1024 N=8192 K=1024, bf16, BN=128 ---
    gemmT<2, 2, 0, 0, 1><<<dim3(64, 4, 1), 512, SHB2, stream>>>(
        WvT, 1024, 0, h, 1024, 0, VT, 8192, 0, bv, nullptr, 0, 0, 1024);

    // --- P_unnorm = exp(Q_b @ K_b^T / 32) bf16 + row-sum partials (no softmax kernel) ---
    gemmT<4, 0, 2, 0, 1><<<dim3(8, 8, 4), 512, SHB4, stream>>>(
        QK, 2048, 4194304LL, QK + 1024, 2048, 4194304LL,
        (short*)S, 4096, 8388608LL, nullptr, (const float*)rowsums, 0, 0, 1024);

    // --- x1 = (P_unnorm @ V_b)/rowsum + x : M=2048 N=1024 K=2048, BN=128 ---
    gemmT<2, 0, 0, 2, 0><<<dim3(8, 8, 4), 512, SHB2, stream>>>(
        (short*)S, 4096, 8388608LL, VT, 8192, 2048LL,
        x1, 1024, 2097152LL, rowsums, x, 1024, 2097152LL, 2048);

    // --- LN2: x1 -> h (bf16) ---
    ln_rows<<<MTOT, 256, 0, stream>>>(x1, ln2g, ln2b, h);

    // --- FF1: ff = gelu(h @ Win + bin) : M=8192 N=4096 K=1024, bf16 (aliases S) ---
    short* ff = (short*)S;
    gemmT<4, 1, 1, 0, 1><<<dim3(16, 32, 1), 512, SHB4, stream>>>(
        h, 1024, 0, WinT, 1024, 0, ff, 4096, 0, bin, nullptr, 0, 0, 1024);

    // --- FF2: out = ff @ Wout + bout + x1 : M=8192 N=1024 K=4096, BN=128 ---
    gemmT<2, 1, 0, 1, 0><<<dim3(8, 32, 1), 512, SHB2, stream>>>(
        ff, 4096, 0, WoutT, 4096, 0, (float*)d_out, 1024, 0, bout,
        x1, 1024, 0, 4096);
}

// Round 15
// 375.086 us; speedup vs baseline: 1.0357x; 1.0357x over previous
//
#include <hip/hip_runtime.h>
#include <hip/hip_bf16.h>

// Problem dims
#define B_    4
#define T_    2048
#define D_    1024
#define DH_   1024
#define DFF_  4096
#define MTOT  (B_ * T_)   // 8192 rows

using f32x4  = __attribute__((ext_vector_type(4))) float;
using bf16x8 = __attribute__((ext_vector_type(8))) short;

__device__ __forceinline__ unsigned short f2bf(float f) {
    unsigned u = __builtin_bit_cast(unsigned, f);
    u += 0x7fffu + ((u >> 16) & 1u);     // round-to-nearest-even
    return (unsigned short)(u >> 16);
}
__device__ __forceinline__ float bf2f(unsigned short h) {
    unsigned u = ((unsigned)h) << 16;
    return __builtin_bit_cast(float, u);
}

// async global->LDS, 16B per lane; LDS dest is wave-uniform base + lane*16
__device__ __forceinline__ void gload16(const short* g, short* l) {
    __builtin_amdgcn_global_load_lds(
        (const __attribute__((address_space(1))) unsigned int*)g,
        (__attribute__((address_space(3))) unsigned int*)l, 16, 0, 0);
}

// ---------------- weight transpose + fp32->bf16 convert ----------------
__global__ __launch_bounds__(256) void transp_f32_bf16(
    const float* __restrict__ src, short* __restrict__ dst, int K, int N) {
    __shared__ float tile[32][33];
    int tk = blockIdx.y * 32, tn = blockIdx.x * 32;
    int tx = threadIdx.x & 31, ty = threadIdx.x >> 5;   // 32 x 8
#pragma unroll
    for (int i = 0; i < 4; i++) {
        int r = ty + i * 8;
        tile[r][tx] = src[(size_t)(tk + r) * N + tn + tx];
    }
    __syncthreads();
#pragma unroll
    for (int i = 0; i < 4; i++) {
        int r = ty + i * 8;   // n offset
        dst[(size_t)(tn + r) * K + tk + tx] = f2bf(tile[tx][r]);
    }
}

__global__ void copyv(const float* __restrict__ s, float* __restrict__ d, int n) {
    int i = blockIdx.x * blockDim.x + threadIdx.x;
    if (i < n) d[i] = s[i];
}

// ---------------- LayerNorm (fp32 in, bf16 out), one block per row ----------------
__global__ __launch_bounds__(256) void ln_rows(
    const float* __restrict__ x, const float* __restrict__ g,
    const float* __restrict__ bta, short* __restrict__ out) {
    int row = blockIdx.x;
    const float* xr = x + (size_t)row * D_;
    int t = threadIdx.x;
    float4 v = *(const float4*)(xr + t * 4);
    float s  = v.x + v.y + v.z + v.w;
    float s2 = v.x * v.x + v.y * v.y + v.z * v.z + v.w * v.w;
#pragma unroll
    for (int off = 1; off < 64; off <<= 1) {
        s  += __shfl_xor(s, off);
        s2 += __shfl_xor(s2, off);
    }
    __shared__ float as_[4], as2_[4];
    int wave = t >> 6, lane = t & 63;
    if (lane == 0) { as_[wave] = s; as2_[wave] = s2; }
    __syncthreads();
    s  = as_[0] + as_[1] + as_[2] + as_[3];
    s2 = as2_[0] + as2_[1] + as2_[2] + as2_[3];
    float mean = s * (1.0f / D_);
    float var  = s2 * (1.0f / D_) - mean * mean;
    float rstd = rsqrtf(var + 1e-5f);
    float4 gv = *(const float4*)(g + t * 4);
    float4 bv = *(const float4*)(bta + t * 4);
    short4 o;
    o.x = f2bf((v.x - mean) * rstd * gv.x + bv.x);
    o.y = f2bf((v.y - mean) * rstd * gv.y + bv.y);
    o.z = f2bf((v.z - mean) * rstd * gv.z + bv.z);
    o.w = f2bf((v.w - mean) * rstd * gv.w + bv.w);
    *(short4*)(out + (size_t)row * D_ + t * 4) = o;
}

// ---------------- tiled GEMM: C[m][n] = sum_k A[m][k]*Bt[n][k] ----------------
// BM=256, BN=64*NB, BK=64, 8 waves (2M x 4N), per-wave 128 x 16*NB (acc[8][NB]).
// r11 data movement, DE-PINNED (r13-best): no manual lgkmcnt / sched_barrier /
// setprio — compiler emits precise counted lgkmcnt between ds_read and MFMA.
// Only vmcnt waits for global_load_lds DMA remain (1 per K-tile) + raw
// s_barrier phase boundaries.
// NB=4 (A 3-slot / B 2-slot, 160 KiB):
//   P1: rd A(m4-7,k0); gl B23(t+1); MFMA aA*b0 -> acc[0..3]
//   P2: rd A(m0-3,k1)+B(k1); gl A02(t+2); MFMA aB*b0 -> acc[4..7]
//   P3: rd A(m4-7,k1); gl A13(t+2); MFMA aA*b1 -> acc[0..3]; vmcnt(4)
//   P4: rd A(m0-3,k0)+B(k0) from slot t+1 (landed); gl B01(t+2); MFMA aB*b1
// NB=2 (3-slot lead-2, 144 KiB):
//   Ph1: rd (A k1, B k1); gl 6 chunks(t+2); MFMA k0; vmcnt(6)
//   Ph2: rd (A k0, B k0) from slot t+1; MFMA k1
// LDS XOR swizzle byte ^= ((row&7)<<4); inverse on global src, linear LDS dest.
// XCD-chunked bijective + 4-wide supertile block order.
// ACT: 0 none, 1 exact GELU, 2 attn-exp (unnormalized P + row-sum partials).
// RES: 0 none, 1 +res, 2 normalize by 8-way row-sum partials then +res.
template<int NB, int BIAS_MODE, int ACT, int RES, int OUT_BF16>
__global__ __launch_bounds__(512, 2) void gemmT(
    const short* __restrict__ A, int lda, long long sA,
    const short* __restrict__ Bt, int ldb, long long sB,
    void* __restrict__ C, int ldc, long long sC,
    const float* __restrict__ bias,
    const float* __restrict__ res, int ldr, long long sR,
    int K) {
    extern __shared__ short smem_[];
    short* shA = smem_;                 // 3 slots x 16384 shorts
    short* shB = smem_ + 49152;         // NB4: 2 x 16384; NB2: 3 x 8192

    // ---- XCD-chunked bijective swizzle + 4-wide bn supertile strips ----
    int gx = gridDim.x, gy = gridDim.y;
    int n2d = gx * gy;
    int nwg = n2d * gridDim.z;
    int lid = blockIdx.x + gx * (blockIdx.y + gy * blockIdx.z);
    int q = nwg >> 3, rq = nwg & 7, xcd = lid & 7, i_ = lid >> 3;
    int nid = (xcd < rq ? xcd * (q + 1) : rq * (q + 1) + (xcd - rq) * q) + i_;
    int z = nid / n2d, r2d = nid % n2d;
    int sw = gy << 2;                          // requires gx % 4 == 0
    int strip = r2d / sw, rr = r2d % sw;
    int by = rr >> 2, bx = (strip << 2) + (rr & 3);

    int bm = by * 256, bn = bx * (64 * NB);
    const short* gA = A  + (size_t)z * sA + (size_t)bm * lda;
    const short* gB = Bt + (size_t)z * sB + (size_t)bn * ldb;
    int tid = threadIdx.x, lane = tid & 63, w = tid >> 6;
    int wr = w >> 2, wc = w & 3;

    // staging: 8KB chunk c = rows c*64..c*64+63; lane covers 16B of a 128B row.
    // global col carries the inverse swizzle; LDS dest linear.
    int rbase = tid >> 3;                                    // 0..63
    int gcol  = ((((tid & 7) << 4) ^ ((rbase & 7) << 4)) >> 1);
    const short* pA[4]; const short* pB[4];
#pragma unroll
    for (int c = 0; c < 4; c++)
        pA[c] = gA + (size_t)(c * 64 + rbase) * lda + gcol;
#pragma unroll
    for (int c = 0; c < NB; c++)
        pB[c] = gB + (size_t)(c * 64 + rbase) * ldb + gcol;

    // fragment ds_read byte offsets (k0 slice); k1 = off ^ 64
    int aoff[8], boff[4];
#pragma unroll
    for (int f = 0; f < 8; f++) {
        int row = wr * 128 + f * 16 + (lane & 15);
        aoff[f] = row * 128 + ((((lane >> 4) * 16)) ^ ((row & 7) << 4));
    }
#pragma unroll
    for (int f = 0; f < NB; f++) {
        int row = wc * (16 * NB) + f * 16 + (lane & 15);
        boff[f] = row * 128 + ((((lane >> 4) * 16)) ^ ((row & 7) << 4));
    }

    int nk = K >> 6;
    f32x4 acc[8][NB] = {};

    if constexpr (NB == 4) {
        // prologue: tile0 full + tile1 minus B23 (14 loads); vmcnt(6) -> tile0 landed
        gload16(pA[0], shA + 0 * 4096 + tid * 8);
        gload16(pA[2], shA + 2 * 4096 + tid * 8);
        gload16(pA[1], shA + 1 * 4096 + tid * 8);
        gload16(pA[3], shA + 3 * 4096 + tid * 8);
        gload16(pB[0], shB + 0 * 4096 + tid * 8);
        gload16(pB[1], shB + 1 * 4096 + tid * 8);
        gload16(pB[2], shB + 2 * 4096 + tid * 8);
        gload16(pB[3], shB + 3 * 4096 + tid * 8);
        gload16(pA[0] + 64, shA + 16384 + 0 * 4096 + tid * 8);
        gload16(pA[2] + 64, shA + 16384 + 2 * 4096 + tid * 8);
        gload16(pA[1] + 64, shA + 16384 + 1 * 4096 + tid * 8);
        gload16(pA[3] + 64, shA + 16384 + 3 * 4096 + tid * 8);
        gload16(pB[0] + 64, shB + 16384 + 0 * 4096 + tid * 8);
        gload16(pB[1] + 64, shB + 16384 + 1 * 4096 + tid * 8);
        asm volatile("s_waitcnt vmcnt(6)" ::: "memory");
        __builtin_amdgcn_s_barrier();

        // preload P1(0) operands: aA = A(m0-3,k0), b0 = B(k0) from slot 0
        bf16x8 aA[4], aB[4], b0[4], b1[4];
        {
            const char* s0A = (const char*)shA;
            const char* s0B = (const char*)shB;
#pragma unroll
            for (int f = 0; f < 4; f++) aA[f] = *(const bf16x8*)(s0A + aoff[f]);
#pragma unroll
            for (int f = 0; f < 4; f++) b0[f] = *(const bf16x8*)(s0B + boff[f]);
        }

#define MF4(r_, av, bv) \
        acc[r_][0] = __builtin_amdgcn_mfma_f32_16x16x32_bf16(av, bv[0], acc[r_][0], 0, 0, 0); \
        acc[r_][1] = __builtin_amdgcn_mfma_f32_16x16x32_bf16(av, bv[1], acc[r_][1], 0, 0, 0); \
        acc[r_][2] = __builtin_amdgcn_mfma_f32_16x16x32_bf16(av, bv[2], acc[r_][2], 0, 0, 0); \
        acc[r_][3] = __builtin_amdgcn_mfma_f32_16x16x32_bf16(av, bv[3], acc[r_][3], 0, 0, 0);

        for (int t = 0; t < nk; t++) {
            const char* sA_  = (const char*)(shA + (t % 3) * 16384);
            const char* sB_  = (const char*)(shB + (t & 1) * 16384);
            const char* sA1_ = (const char*)(shA + ((t + 1) % 3) * 16384);
            const char* sB1_ = (const char*)(shB + ((t + 1) & 1) * 16384);
            short* wA2 = shA + ((t + 2) % 3) * 16384;   // A(t+2)
            short* wB1 = shB + ((t + 1) & 1) * 16384;   // B(t+1) remainder B23
            short* wB2 = shB + (t & 1) * 16384;         // B(t+2)
            int ka  = (t + 2 < nk ? t + 2 : nk - 1) << 6;
            int kb1 = (t + 1 < nk ? t + 1 : nk - 1) << 6;

            // ---- P1: rd aB<-A(m4-7,k0); gl B23(t+1); MFMA aA*b0 -> acc[0..3] ----
#pragma unroll
            for (int f = 0; f < 4; f++) aB[f] = *(const bf16x8*)(sA_ + aoff[4 + f]);
            gload16(pB[2] + kb1, wB1 + 2 * 4096 + tid * 8);
            gload16(pB[3] + kb1, wB1 + 3 * 4096 + tid * 8);
            MF4(0, aA[0], b0) MF4(1, aA[1], b0) MF4(2, aA[2], b0) MF4(3, aA[3], b0)
            __builtin_amdgcn_s_barrier();
            // ---- P2: rd aA<-A(m0-3,k1), b1<-B(k1); gl A02(t+2); MFMA aB*b0 -> acc[4..7] ----
#pragma unroll
            for (int f = 0; f < 4; f++) aA[f] = *(const bf16x8*)(sA_ + (aoff[f] ^ 64));
#pragma unroll
            for (int f = 0; f < 4; f++) b1[f] = *(const bf16x8*)(sB_ + (boff[f] ^ 64));
            gload16(pA[0] + ka, wA2 + 0 * 4096 + tid * 8);
            gload16(pA[2] + ka, wA2 + 2 * 4096 + tid * 8);
            MF4(4, aB[0], b0) MF4(5, aB[1], b0) MF4(6, aB[2], b0) MF4(7, aB[3], b0)
            __builtin_amdgcn_s_barrier();
            // ---- P3: rd aB<-A(m4-7,k1); gl A13(t+2); MFMA aA*b1 -> acc[0..3]; vmcnt(4) ----
#pragma unroll
            for (int f = 0; f < 4; f++) aB[f] = *(const bf16x8*)(sA_ + (aoff[4 + f] ^ 64));
            gload16(pA[1] + ka, wA2 + 1 * 4096 + tid * 8);
            gload16(pA[3] + ka, wA2 + 3 * 4096 + tid * 8);
            MF4(0, aA[0], b1) MF4(1, aA[1], b1) MF4(2, aA[2], b1) MF4(3, aA[3], b1)
            asm volatile("s_waitcnt vmcnt(4)" ::: "memory");  // tile t+1 fully landed
            __builtin_amdgcn_s_barrier();
            // ---- P4: rd aA<-A(t+1,m0-3,k0), b0<-B(t+1,k0); gl B01(t+2); MFMA aB*b1 ----
#pragma unroll
            for (int f = 0; f < 4; f++) aA[f] = *(const bf16x8*)(sA1_ + aoff[f]);
#pragma unroll
            for (int f = 0; f < 4; f++) b0[f] = *(const bf16x8*)(sB1_ + boff[f]);
            gload16(pB[0] + ka, wB2 + 0 * 4096 + tid * 8);
            gload16(pB[1] + ka, wB2 + 1 * 4096 + tid * 8);
            MF4(4, aB[0], b1) MF4(5, aB[1], b1) MF4(6, aB[2], b1) MF4(7, aB[3], b1)
            __builtin_amdgcn_s_barrier();
        }
#undef MF4
    } else {
        // prologue: stage tiles 0,1 into slots 0,1 (12 loads); vmcnt(6) -> tile0 landed
#pragma unroll
        for (int s = 0; s < 2; s++) {
#pragma unroll
            for (int c = 0; c < 4; c++)
                gload16(pA[c] + s * 64, shA + s * 16384 + c * 4096 + tid * 8);
#pragma unroll
            for (int c = 0; c < 2; c++)
                gload16(pB[c] + s * 64, shB + s * 8192 + c * 4096 + tid * 8);
        }
        asm volatile("s_waitcnt vmcnt(6)" ::: "memory");
        __builtin_amdgcn_s_barrier();

        // preload Ph1(0) operands: aA = A(k0), b0 = B(k0) from slot 0
        bf16x8 aA[8], aB[8], b0[2], b1[2];
        {
            const char* s0A = (const char*)shA;
            const char* s0B = (const char*)shB;
#pragma unroll
            for (int f = 0; f < 8; f++) aA[f] = *(const bf16x8*)(s0A + aoff[f]);
#pragma unroll
            for (int f = 0; f < 2; f++) b0[f] = *(const bf16x8*)(s0B + boff[f]);
        }

#define MF2(r_, av, bv) \
        acc[r_][0] = __builtin_amdgcn_mfma_f32_16x16x32_bf16(av, bv[0], acc[r_][0], 0, 0, 0); \
        acc[r_][1] = __builtin_amdgcn_mfma_f32_16x16x32_bf16(av, bv[1], acc[r_][1], 0, 0, 0);

        for (int t = 0; t < nk; t++) {
            const char* sA_  = (const char*)(shA + (t % 3) * 16384);
            const char* sB_  = (const char*)(shB + (t % 3) * 8192);
            const char* sA1_ = (const char*)(shA + ((t + 1) % 3) * 16384);
            const char* sB1_ = (const char*)(shB + ((t + 1) % 3) * 8192);
            short* wA = shA + ((t + 2) % 3) * 16384;
            short* wB = shB + ((t + 2) % 3) * 8192;
            int ks = (t + 2 < nk ? t + 2 : nk - 1) << 6;

            // ---- Ph1: rd (aB<-A k1, b1<-B k1); gl 6 chunks(t+2); MFMA k0; vmcnt(6) ----
#pragma unroll
            for (int f = 0; f < 8; f++) aB[f] = *(const bf16x8*)(sA_ + (aoff[f] ^ 64));
#pragma unroll
            for (int f = 0; f < 2; f++) b1[f] = *(const bf16x8*)(sB_ + (boff[f] ^ 64));
            gload16(pA[0] + ks, wA + tid * 8);
            gload16(pA[1] + ks, wA + 4096 + tid * 8);
            gload16(pA[2] + ks, wA + 2 * 4096 + tid * 8);
            gload16(pA[3] + ks, wA + 3 * 4096 + tid * 8);
            gload16(pB[0] + ks, wB + tid * 8);
            gload16(pB[1] + ks, wB + 4096 + tid * 8);
            MF2(0, aA[0], b0) MF2(1, aA[1], b0) MF2(2, aA[2], b0) MF2(3, aA[3], b0)
            MF2(4, aA[4], b0) MF2(5, aA[5], b0) MF2(6, aA[6], b0) MF2(7, aA[7], b0)
            asm volatile("s_waitcnt vmcnt(6)" ::: "memory");  // tile t+1 landed
            __builtin_amdgcn_s_barrier();
            // ---- Ph2: rd (aA<-A(t+1) k0, b0<-B(t+1) k0) from slot t+1; MFMA k1 ----
#pragma unroll
            for (int f = 0; f < 8; f++) aA[f] = *(const bf16x8*)(sA1_ + aoff[f]);
#pragma unroll
            for (int f = 0; f < 2; f++) b0[f] = *(const bf16x8*)(sB1_ + boff[f]);
            MF2(0, aB[0], b1) MF2(1, aB[1], b1) MF2(2, aB[2], b1) MF2(3, aB[3], b1)
            MF2(4, aB[4], b1) MF2(5, aB[5], b1) MF2(6, aB[6], b1) MF2(7, aB[7], b1)
            __builtin_amdgcn_s_barrier();
        }
#undef MF2
    }
    asm volatile("s_waitcnt vmcnt(0)" ::: "memory");   // drain DMA before epilogue
    __syncthreads();   // all waves' DMAs landed before anyone writes lpart

    // epilogue: C/D layout col = lane&15, row = (lane>>4)*4 + r  [m89/m91 verified]
    size_t zc = (size_t)z * (size_t)sC;
    float* lpart = (float*)smem_;   // [4 wc][256 rows] reuse (ACT==2)
#pragma unroll
    for (int fr = 0; fr < 8; fr++) {
        float pr[4] = {0.f, 0.f, 0.f, 0.f};
        float s8[4];
        if (RES == 2) {
#pragma unroll
            for (int r_ = 0; r_ < 4; r_++) {
                int row = bm + wr * 128 + fr * 16 + (lane >> 4) * 4 + r_;
                float s = 0.f;
#pragma unroll
                for (int i = 0; i < 8; i++) s += bias[((size_t)z * 8 + i) * 2048 + row];
                s8[r_] = 1.0f / s;
            }
        }
#pragma unroll
        for (int fn = 0; fn < NB; fn++) {
            int colc = bn + wc * (16 * NB) + fn * 16 + (lane & 15);
#pragma unroll
            for (int r_ = 0; r_ < 4; r_++) {
                int row = bm + wr * 128 + fr * 16 + (lane >> 4) * 4 + r_;
                float v = acc[fr][fn][r_];
                if (BIAS_MODE == 1) v += bias[colc];
                else if (BIAS_MODE == 2) v += bias[row];
                if (ACT == 1) v = 0.5f * v * (1.0f + erff(v * 0.70710678118654752f));
                if (ACT == 2) {
                    // unnormalized attention prob: no max-subtraction needed
                    v = expf(v * 0.03125f);
                    unsigned short us = f2bf(v);
                    ((short*)C)[zc + (size_t)row * ldc + colc] = (short)us;
                    pr[r_] += bf2f(us);   // sum ROUNDED values -> exact normalization
                    continue;
                }
                if (RES == 1) v += res[(size_t)z * sR + (size_t)row * ldr + colc];
                if (RES == 2) v = v * s8[r_] + res[(size_t)z * sR + (size_t)row * ldr + colc];
                if (OUT_BF16) ((short*)C)[zc + (size_t)row * ldc + colc] = f2bf(v);
                else          ((float*)C)[zc + (size_t)row * ldc + colc] = v;
            }
        }
        if (ACT == 2) {
            // reduce across the 16 lanes sharing each row (cols), deterministic
#pragma unroll
            for (int m_ = 1; m_ < 16; m_ <<= 1) {
#pragma unroll
                for (int r_ = 0; r_ < 4; r_++) pr[r_] += __shfl_xor(pr[r_], m_);
            }
            if ((lane & 15) == 0) {
#pragma unroll
                for (int r_ = 0; r_ < 4; r_++)
                    lpart[wc * 256 + wr * 128 + fr * 16 + (lane >> 4) * 4 + r_] = pr[r_];
            }
        }
    }
    if (ACT == 2) {
        __syncthreads();
        if (tid < 256) {
            float s = lpart[tid] + lpart[256 + tid] + lpart[512 + tid] + lpart[768 + tid];
            ((float*)res)[((size_t)z * 8 + bx) * 2048 + bm + tid] = s;
        }
    }
}

#define SHB4 163840   // NB=4: A 3x32KB + B 2x32KB
#define SHB2 147456   // NB=2: 3 slots x (16384+8192) shorts

extern "C" void kernel_launch(void* const* d_in, const int* in_sizes, int n_in,
                              void* d_out, int out_size, void* d_ws, size_t ws_size,
                              hipStream_t stream) {
    const float* x    = (const float*)d_in[0];
    const float* ln1g = (const float*)d_in[1];
    const float* ln1b = (const float*)d_in[2];
    const float* Wq   = (const float*)d_in[3];
    const float* bq   = (const float*)d_in[4];
    const float* Wk   = (const float*)d_in[5];
    const float* bk   = (const float*)d_in[6];
    const float* Wv   = (const float*)d_in[7];
    const float* bv   = (const float*)d_in[8];
    const float* ln2g = (const float*)d_in[9];
    const float* ln2b = (const float*)d_in[10];
    const float* Win  = (const float*)d_in[11];
    const float* bin  = (const float*)d_in[12];
    const float* Wout = (const float*)d_in[13];
    const float* bout = (const float*)d_in[14];

    char* ws = (char*)d_ws;
    size_t off = 0;
    auto alloc = [&](size_t bytes) {
        void* p = ws + off;
        off += (bytes + 255) & ~(size_t)255;
        return p;
    };
    short* WqkT  = (short*)alloc((size_t)2048 * 1024 * 2);  // [2048][1024] = [Wq^T ; Wk^T]
    short* WvT   = (short*)alloc((size_t)1024 * 1024 * 2);  // [1024][1024]
    short* WinT  = (short*)alloc((size_t)4096 * 1024 * 2);  // [4096][1024]
    short* WoutT = (short*)alloc((size_t)1024 * 4096 * 2);  // [1024][4096]
    float* bqk   = (float*)alloc((size_t)2048 * 4);
    short* h     = (short*)alloc((size_t)MTOT * 1024 * 2);  // LN output (reused for LN2)
    short* QK    = (short*)alloc((size_t)MTOT * 2048 * 2);  // [8192][2048] = [Q | K]
    short* VT    = (short*)alloc((size_t)1024 * 8192 * 2);  // V^T [1024][8192]
    float* S     = (float*)alloc((size_t)4 * 2048 * 2048 * 4); // P bf16 (ld 4096 sh) + ff alias
    float* x1    = (float*)alloc((size_t)MTOT * 1024 * 4);  // x + attn_out (fp32)
    float* rowsums = (float*)alloc((size_t)4 * 8 * 2048 * 4); // per-bn-block partial row sums
    (void)ws_size; (void)in_sizes; (void)n_in; (void)out_size;

    hipFuncSetAttribute((const void*)gemmT<4,1,0,0,1>, hipFuncAttributeMaxDynamicSharedMemorySize, SHB4);
    hipFuncSetAttribute((const void*)gemmT<4,0,2,0,1>, hipFuncAttributeMaxDynamicSharedMemorySize, SHB4);
    hipFuncSetAttribute((const void*)gemmT<4,1,1,0,1>, hipFuncAttributeMaxDynamicSharedMemorySize, SHB4);
    hipFuncSetAttribute((const void*)gemmT<2,2,0,0,1>, hipFuncAttributeMaxDynamicSharedMemorySize, SHB2);
    hipFuncSetAttribute((const void*)gemmT<2,0,0,2,0>, hipFuncAttributeMaxDynamicSharedMemorySize, SHB2);
    hipFuncSetAttribute((const void*)gemmT<2,1,0,1,0>, hipFuncAttributeMaxDynamicSharedMemorySize, SHB2);

    // --- weights -> bf16 [N][K] ---
    transp_f32_bf16<<<dim3(32, 32), 256, 0, stream>>>(Wq, WqkT, 1024, 1024);
    transp_f32_bf16<<<dim3(32, 32), 256, 0, stream>>>(Wk, WqkT + (size_t)1024 * 1024, 1024, 1024);
    transp_f32_bf16<<<dim3(32, 32), 256, 0, stream>>>(Wv, WvT, 1024, 1024);
    transp_f32_bf16<<<dim3(128, 32), 256, 0, stream>>>(Win, WinT, 1024, 4096);
    transp_f32_bf16<<<dim3(32, 128), 256, 0, stream>>>(Wout, WoutT, 4096, 1024);
    copyv<<<4, 256, 0, stream>>>(bq, bqk, 1024);
    copyv<<<4, 256, 0, stream>>>(bk, bqk + 1024, 1024);

    // --- LN1: x -> h (bf16) ---
    ln_rows<<<MTOT, 256, 0, stream>>>(x, ln1g, ln1b, h);

    // --- [Q|K] = h @ [Wq|Wk] + bias : M=8192 N=2048 K=1024, bf16 ---
    gemmT<4, 1, 0, 0, 1><<<dim3(8, 32, 1), 512, SHB4, stream>>>(
        h, 1024, 0, WqkT, 1024, 0, QK, 2048, 0, bqk, nullptr, 0, 0, 1024);

    // --- V^T = Wv^T @ h^T + bv(row): M=1024 N=8192 K=1024, bf16, BN=128 (full chip) ---
    gemmT<2, 2, 0, 0, 1><<<dim3(64, 4, 1), 512, SHB2, stream>>>(
        WvT, 1024, 0, h, 1024, 0, VT, 8192, 0, bv, nullptr, 0, 0, 1024);

    // --- P_unnorm = exp(Q_b @ K_b^T / 32) bf16 + row-sum partials (no softmax kernel) ---
    gemmT<4, 0, 2, 0, 1><<<dim3(8, 8, 4), 512, SHB4, stream>>>(
        QK, 2048, 4194304LL, QK + 1024, 2048, 4194304LL,
        (short*)S, 4096, 8388608LL, nullptr, (const float*)rowsums, 0, 0, 1024);

    // --- x1 = (P_unnorm @ V_b)/rowsum + x : M=2048 N=1024 K=2048, BN=128 (full chip) ---
    gemmT<2, 0, 0, 2, 0><<<dim3(8, 8, 4), 512, SHB2, stream>>>(
        (short*)S, 4096, 8388608LL, VT, 8192, 2048LL,
        x1, 1024, 2097152LL, rowsums, x, 1024, 2097152LL, 2048);

    // --- LN2: x1 -> h (bf16) ---
    ln_rows<<<MTOT, 256, 0, stream>>>(x1, ln2g, ln2b, h);

    // --- FF1: ff = gelu(h @ Win + bin) : M=8192 N=4096 K=1024, bf16 (aliases S) ---
    short* ff = (short*)S;
    gemmT<4, 1, 1, 0, 1><<<dim3(16, 32, 1), 512, SHB4, stream>>>(
        h, 1024, 0, WinT, 1024, 0, ff, 4096, 0, bin, nullptr, 0, 0, 1024);

    // --- FF2: out = ff @ Wout + bout + x1 : M=8192 N=1024 K=4096, BN=128 (full chip) ---
    gemmT<2, 1, 0, 1, 0><<<dim3(8, 32, 1), 512, SHB2, stream>>>(
        ff, 4096, 0, WoutT, 4096, 0, (float*)d_out, 1024, 0, bout,
        x1, 1024, 0, 4096);
}